// Round 3
// baseline (95.410 us; speedup 1.0000x reference)
//
#include <hip/hip_runtime.h>
#include <math.h>

#define TILE  512
#define BLOCK 256
#define NC    128

// ws layout: scal (12 floats) at +0 ; pbmin (NB * NC floats, block-major) at +256.

// Init: compute camera scalars ONCE in double precision (bit-matched the np
// reference in R1/R2: absmax 0.0).
__global__ void init_kernel(const float* __restrict__ theta,
                            const float* __restrict__ vang,
                            const int* __restrict__ hh,
                            const int* __restrict__ ww,
                            float* __restrict__ scal) {
    if (threadIdx.x == 0) {
        const double D2R = 0.017453292519943295;
        double a = (double)theta[0] * D2R;
        double b = (double)theta[1] * D2R;
        double c = (double)theta[2] * D2R;
        double sa = sin(a), ca = cos(a);
        double sb = sin(b), cb = cos(b);
        double sc = sin(c), cc = cos(c);
        double H = (double)hh[0], W = (double)ww[0];
        double fd = -H / (2.0 * tan((double)vang[0] * 0.5 * D2R));
        // R = Rz @ Ry @ Rx
        scal[0] = (float)(cc * cb);
        scal[1] = (float)(cc * sb * sa - sc * ca);
        scal[2] = (float)(cc * sb * ca + sc * sa);
        scal[3] = (float)(sc * cb);
        scal[4] = (float)(sc * sb * sa + cc * ca);
        scal[5] = (float)(sc * sb * ca - cc * sa);
        scal[6] = (float)(-sb);
        scal[7] = (float)(cb * sa);
        scal[8] = (float)(cb * ca);
        scal[9]  = (float)fd;                 // f
        scal[10] = (float)(W * 0.5 - 0.5);    // cx
        scal[11] = (float)(H * 0.5 + 0.5);    // H - cy (v-flip offset)
    }
}

// One block per 512-point tile.
// Phase 1: project tile -> LDS as (u, v_flipped, ||b||^2, 0).
// Phase 2: each lane owns 4 corners (folded consts -2ax,-2ay in regs); the
// wave's two 32-lane halves scan disjoint 64-point ranges (2-way LDS
// aliasing = free). 3 VALU per (corner,point) pair.
// Tail: block minima stored COALESCED (512 B contiguous) to pbmin[block][*].
__global__ __launch_bounds__(BLOCK) void proj_min_kernel(
        const float* __restrict__ pnt,
        const float* __restrict__ cor,
        const float* __restrict__ cam,
        const float* __restrict__ scal,
        float* __restrict__ pbmin,
        int n) {
    __shared__ float4 uvb[TILE];
    __shared__ float red[4 * NC];   // [wave][corner]

    const int tid = threadIdx.x;
    const float r00 = scal[0], r01 = scal[1], r02 = scal[2];
    const float r10 = scal[3], r11 = scal[4], r12 = scal[5];
    const float r20 = scal[6], r21 = scal[7], r22 = scal[8];
    const float f = scal[9], cx = scal[10], cyv = scal[11];
    const float c0 = cam[0], c1 = cam[1], c2 = cam[2];

    const int base = blockIdx.x * TILE;

    #pragma unroll
    for (int k = 0; k < TILE; k += BLOCK) {
        int i = base + k + tid;
        float u = 0.f, vf = 0.f, b2 = 3.0e38f;   // masked points never win min
        if (i < n) {
            float px = pnt[3 * i], py = pnt[3 * i + 1], pz = pnt[3 * i + 2];
            float tx = px - c0, ty = py - c1, tz = pz - c2;
            float x = fmaf(r00, tx, fmaf(r01, ty, r02 * tz));
            float y = fmaf(r10, tx, fmaf(r11, ty, r12 * tz));
            float z = fmaf(r20, tx, fmaf(r21, ty, r22 * tz));
            float xz = x / z, yz = y / z;        // match reference's true divide
            u  = fmaf(f, xz, cx);
            vf = fmaf(-f, yz, cyv);              // H - (f*y/z + cy)
            b2 = fmaf(u, u, vf * vf);
        }
        uvb[k + tid] = make_float4(u, vf, b2, 0.f);
    }
    __syncthreads();

    const int lane = tid & 63;
    const int w    = tid >> 6;        // wave id
    const int h    = lane >> 5;       // half-wave: which 64-point subrange
    const int sl   = lane & 31;
    const int cb   = sl << 2;         // this lane's 4 corners: cb..cb+3

    float bx[4], by[4], m[4];
    #pragma unroll
    for (int k = 0; k < 4; ++k) {
        bx[k] = -2.f * cor[2 * (cb + k)];
        by[k] = -2.f * cor[2 * (cb + k) + 1];
        m[k]  = 3.4e38f;
    }

    const float4* p = &uvb[(w << 7) + (h << 6)];
    #pragma unroll 8
    for (int j = 0; j < 64; ++j) {
        float4 q = p[j];              // broadcast within each half-wave
        #pragma unroll
        for (int k = 0; k < 4; ++k)
            m[k] = fminf(m[k], fmaf(bx[k], q.x, fmaf(by[k], q.y, q.z)));
    }

    // fold the two half-wave scans
    #pragma unroll
    for (int k = 0; k < 4; ++k)
        m[k] = fminf(m[k], __shfl_xor(m[k], 32));
    if (lane < 32) {
        #pragma unroll
        for (int k = 0; k < 4; ++k)
            red[w * NC + cb + k] = m[k];
    }
    __syncthreads();

    if (tid < NC) {   // cross-wave min, coalesced block-major store
        float mm = fminf(fminf(red[tid], red[NC + tid]),
                         fminf(red[2 * NC + tid], red[3 * NC + tid]));
        pbmin[blockIdx.x * NC + tid] = mm;
    }
}

// ONE block, 1024 threads, zero atomics. Coalesced min over pbmin[NB][NC]
// (8 row-groups x 128 corners), LDS fold, +||a||^2, fp64-ordered final sum.
__global__ __launch_bounds__(1024) void reduce_kernel(
        const float* __restrict__ pbmin,
        const float* __restrict__ cor,
        float* __restrict__ out, int NB) {
    __shared__ float part[8][NC];
    const int t = threadIdx.x;
    const int c = t & (NC - 1);
    const int g = t >> 7;             // row group 0..7
    float m = 3.4e38f;
    for (int i = g; i < NB; i += 8)
        m = fminf(m, pbmin[i * NC + c]);   // consecutive t -> consecutive addr
    part[g][c] = m;
    __syncthreads();
    if (t < NC) {
        float mm = part[0][t];
        #pragma unroll
        for (int g2 = 1; g2 < 8; ++g2) mm = fminf(mm, part[g2][t]);
        float ax = cor[2 * t], ay = cor[2 * t + 1];
        part[0][t] = mm + fmaf(ax, ax, ay * ay);
    }
    __syncthreads();
    if (t == 0) {
        double s = 0.0;
        #pragma unroll 8
        for (int i = 0; i < NC; ++i) s += (double)part[0][i];
        out[0] = (float)s;
    }
}

extern "C" void kernel_launch(void* const* d_in, const int* in_sizes, int n_in,
                              void* d_out, int out_size, void* d_ws, size_t ws_size,
                              hipStream_t stream) {
    const float* pnt   = (const float*)d_in[0];  // (400000,3)
    const float* cor   = (const float*)d_in[1];  // (128,2)
    const float* cam   = (const float*)d_in[2];  // (3,)
    const float* theta = (const float*)d_in[3];  // (3,)
    const float* vang  = (const float*)d_in[4];  // (1,)
    const int*   hh    = (const int*)d_in[5];    // scalar int
    const int*   ww    = (const int*)d_in[6];    // scalar int

    int n  = in_sizes[0] / 3;
    int NB = (n + TILE - 1) / TILE;

    float* scal  = (float*)d_ws;                     // 12 floats
    float* pbmin = (float*)((char*)d_ws + 256);      // NB * NC floats, block-major

    init_kernel<<<1, 64, 0, stream>>>(theta, vang, hh, ww, scal);
    proj_min_kernel<<<NB, BLOCK, 0, stream>>>(pnt, cor, cam, scal, pbmin, n);
    reduce_kernel<<<1, 1024, 0, stream>>>(pbmin, cor, (float*)d_out, NB);
}

// Round 4
// 79.725 us; speedup vs baseline: 1.1967x; 1.1967x over previous
//
#include <hip/hip_runtime.h>
#include <math.h>

#define TILE  512
#define BLOCK 256
#define NC    128

// ws layout: pbmin (NB*NC floats, block-major) at +0 ; stage (NC floats) at +448K.

// One block per 512-point tile. Camera scalars computed per-block in fp64 by
// thread 0 (bit-matched np in R1-R3; only 1 of 4 waves pays the trig).
// Phase 1: coalesced float2 point loads (thread t owns points 2t,2t+1),
//          project -> LDS (u, v_flipped, ||b||^2, 0).
// Phase 2: lane owns 4 corners; half-waves scan disjoint 64-pt ranges
//          (2-way LDS aliasing = free). 3 VALU per pair.
// Tail: per-block corner minima stored coalesced to pbmin[block][*].
__global__ __launch_bounds__(BLOCK) void proj_min_kernel(
        const float* __restrict__ pnt,
        const float* __restrict__ cor,
        const float* __restrict__ cam,
        const float* __restrict__ theta,
        const float* __restrict__ vang,
        const int* __restrict__ hh,
        const int* __restrict__ ww,
        float* __restrict__ pbmin,
        int n) {
    __shared__ float4 uvb[TILE];
    __shared__ float red[4 * NC];
    __shared__ float sc[12];

    const int tid  = threadIdx.x;
    const int base = blockIdx.x * TILE;

    // ---- coalesced point prefetch (before trig: hides HBM latency) ----
    const int i0 = base + 2 * tid;
    float p0x = 0.f, p0y = 0.f, p0z = 0.f;
    float p1x = 0.f, p1y = 0.f, p1z = 0.f;
    const bool v0 = (i0 < n), v1 = (i0 + 1 < n);
    if (v1) {
        const float2* q = (const float2*)(pnt + 3 * i0);
        float2 a = q[0], b = q[1], c = q[2];        // x0 y0 | z0 x1 | y1 z1
        p0x = a.x; p0y = a.y; p0z = b.x;
        p1x = b.y; p1y = c.x; p1z = c.y;
    } else if (v0) {
        p0x = pnt[3 * i0]; p0y = pnt[3 * i0 + 1]; p0z = pnt[3 * i0 + 2];
    }

    // ---- fp64 camera scalars, once per block ----
    if (tid == 0) {
        const double D2R = 0.017453292519943295;
        double a = (double)theta[0] * D2R;
        double b = (double)theta[1] * D2R;
        double c = (double)theta[2] * D2R;
        double sa = sin(a), ca = cos(a);
        double sb = sin(b), cb = cos(b);
        double sc_ = sin(c), cc = cos(c);
        double H = (double)hh[0], W = (double)ww[0];
        double fd = -H / (2.0 * tan((double)vang[0] * 0.5 * D2R));
        sc[0] = (float)(cc * cb);
        sc[1] = (float)(cc * sb * sa - sc_ * ca);
        sc[2] = (float)(cc * sb * ca + sc_ * sa);
        sc[3] = (float)(sc_ * cb);
        sc[4] = (float)(sc_ * sb * sa + cc * ca);
        sc[5] = (float)(sc_ * sb * ca - cc * sa);
        sc[6] = (float)(-sb);
        sc[7] = (float)(cb * sa);
        sc[8] = (float)(cb * ca);
        sc[9]  = (float)fd;               // f
        sc[10] = (float)(W * 0.5 - 0.5);  // cx
        sc[11] = (float)(H * 0.5 + 0.5);  // H - cy (v-flip offset)
    }
    __syncthreads();

    const float r00 = sc[0], r01 = sc[1], r02 = sc[2];
    const float r10 = sc[3], r11 = sc[4], r12 = sc[5];
    const float r20 = sc[6], r21 = sc[7], r22 = sc[8];
    const float f = sc[9], cx = sc[10], cyv = sc[11];
    const float c0 = cam[0], c1 = cam[1], c2 = cam[2];

    {   // project the two owned points -> LDS
        float u0 = 0.f, w0 = 0.f, b20 = 3.0e38f;
        float u1 = 0.f, w1 = 0.f, b21 = 3.0e38f;
        if (v0) {
            float tx = p0x - c0, ty = p0y - c1, tz = p0z - c2;
            float x = fmaf(r00, tx, fmaf(r01, ty, r02 * tz));
            float y = fmaf(r10, tx, fmaf(r11, ty, r12 * tz));
            float z = fmaf(r20, tx, fmaf(r21, ty, r22 * tz));
            float xz = x / z, yz = y / z;            // true divide, matches np
            u0 = fmaf(f, xz, cx);
            w0 = fmaf(-f, yz, cyv);
            b20 = fmaf(u0, u0, w0 * w0);
        }
        if (v1) {
            float tx = p1x - c0, ty = p1y - c1, tz = p1z - c2;
            float x = fmaf(r00, tx, fmaf(r01, ty, r02 * tz));
            float y = fmaf(r10, tx, fmaf(r11, ty, r12 * tz));
            float z = fmaf(r20, tx, fmaf(r21, ty, r22 * tz));
            float xz = x / z, yz = y / z;
            u1 = fmaf(f, xz, cx);
            w1 = fmaf(-f, yz, cyv);
            b21 = fmaf(u1, u1, w1 * w1);
        }
        uvb[2 * tid]     = make_float4(u0, w0, b20, 0.f);
        uvb[2 * tid + 1] = make_float4(u1, w1, b21, 0.f);
    }
    __syncthreads();

    const int lane = tid & 63;
    const int w    = tid >> 6;        // wave id
    const int h    = lane >> 5;       // half-wave subrange
    const int sl   = lane & 31;
    const int cb   = sl << 2;         // this lane's 4 corners

    float bx[4], by[4], m[4];
    #pragma unroll
    for (int k = 0; k < 4; ++k) {
        bx[k] = -2.f * cor[2 * (cb + k)];
        by[k] = -2.f * cor[2 * (cb + k) + 1];
        m[k]  = 3.4e38f;
    }

    const float4* p = &uvb[(w << 7) + (h << 6)];
    #pragma unroll 8
    for (int j = 0; j < 64; ++j) {
        float4 q = p[j];
        #pragma unroll
        for (int k = 0; k < 4; ++k)
            m[k] = fminf(m[k], fmaf(bx[k], q.x, fmaf(by[k], q.y, q.z)));
    }

    #pragma unroll
    for (int k = 0; k < 4; ++k)
        m[k] = fminf(m[k], __shfl_xor(m[k], 32));
    if (lane < 32) {
        #pragma unroll
        for (int k = 0; k < 4; ++k)
            red[w * NC + cb + k] = m[k];
    }
    __syncthreads();

    if (tid < NC) {
        float mm = fminf(fminf(red[tid], red[NC + tid]),
                         fminf(red[2 * NC + tid], red[3 * NC + tid]));
        pbmin[blockIdx.x * NC + tid] = mm;
    }
}

// One block per corner, 64 threads: column min over pbmin[*][c] (13 rounds of
// independent scattered loads, 128-way block parallelism), +||a||^2, plain
// store to stage[c]. Zero atomics.
__global__ __launch_bounds__(64) void colmin_kernel(
        const float* __restrict__ pbmin,
        const float* __restrict__ cor,
        float* __restrict__ stage, int NB) {
    const int c = blockIdx.x;
    const int t = threadIdx.x;
    float m = 3.4e38f;
    for (int r = t; r < NB; r += 64)
        m = fminf(m, pbmin[r * NC + c]);
    #pragma unroll
    for (int off = 32; off > 0; off >>= 1)
        m = fminf(m, __shfl_down(m, off));
    if (t == 0) {
        float ax = cor[2 * c], ay = cor[2 * c + 1];
        stage[c] = m + fmaf(ax, ax, ay * ay);
    }
}

// One wave: fp64 tree-sum of 128 corner results (order-insensitive at fp32
// output precision), plain store.
__global__ void sum_kernel(const float* __restrict__ stage,
                           float* __restrict__ out) {
    const int t = threadIdx.x;   // 64 threads
    double s = (double)stage[t] + (double)stage[t + 64];
    #pragma unroll
    for (int off = 32; off > 0; off >>= 1)
        s += __shfl_down(s, off);
    if (t == 0) out[0] = (float)s;
}

extern "C" void kernel_launch(void* const* d_in, const int* in_sizes, int n_in,
                              void* d_out, int out_size, void* d_ws, size_t ws_size,
                              hipStream_t stream) {
    const float* pnt   = (const float*)d_in[0];  // (400000,3)
    const float* cor   = (const float*)d_in[1];  // (128,2)
    const float* cam   = (const float*)d_in[2];  // (3,)
    const float* theta = (const float*)d_in[3];  // (3,)
    const float* vang  = (const float*)d_in[4];  // (1,)
    const int*   hh    = (const int*)d_in[5];    // scalar int
    const int*   ww    = (const int*)d_in[6];    // scalar int

    int n  = in_sizes[0] / 3;
    int NB = (n + TILE - 1) / TILE;

    float* pbmin = (float*)d_ws;                          // NB*NC floats
    float* stage = (float*)((char*)d_ws + 448 * 1024);    // NC floats

    proj_min_kernel<<<NB, BLOCK, 0, stream>>>(pnt, cor, cam, theta, vang,
                                              hh, ww, pbmin, n);
    colmin_kernel<<<NC, 64, 0, stream>>>(pbmin, cor, stage, NB);
    sum_kernel<<<1, 64, 0, stream>>>(stage, (float*)d_out);
}